// Round 9
// baseline (498.213 us; speedup 1.0000x reference)
//
#include <hip/hip_runtime.h>

typedef __bf16 bf16_t;
typedef __bf16 bf16x4 __attribute__((ext_vector_type(4)));
typedef __bf16 bf16x8 __attribute__((ext_vector_type(8)));
typedef float  f32x4  __attribute__((ext_vector_type(4)));

#define LN_EPS 1e-5f

__device__ __forceinline__ void g2l16(const bf16_t* g, bf16_t* l) {
    __builtin_amdgcn_global_load_lds(
        (const __attribute__((address_space(1))) void*)g,
        (__attribute__((address_space(3))) void*)l, 16, 0, 0);
}

// counted vmem wait (immediate-only) + raw barrier with compiler fence
template<int N> __device__ __forceinline__ void wait_vm() {
    if constexpr (N == 0)       asm volatile("s_waitcnt vmcnt(0)" ::: "memory");
    else if constexpr (N == 2)  asm volatile("s_waitcnt vmcnt(2)" ::: "memory");
    else if constexpr (N == 3)  asm volatile("s_waitcnt vmcnt(3)" ::: "memory");
    else if constexpr (N == 4)  asm volatile("s_waitcnt vmcnt(4)" ::: "memory");
    else if constexpr (N == 6)  asm volatile("s_waitcnt vmcnt(6)" ::: "memory");
    else if constexpr (N == 8)  asm volatile("s_waitcnt vmcnt(8)" ::: "memory");
    else if constexpr (N == 12) asm volatile("s_waitcnt vmcnt(12)" ::: "memory");
    else                        asm volatile("s_waitcnt vmcnt(0)" ::: "memory");
}
__device__ __forceinline__ void block_bar() {
    __builtin_amdgcn_s_barrier();
    asm volatile("" ::: "memory");
}

// ---------------------------------------------------------------------------
// fp32 -> bf16 elementwise convert (n multiple of 1024).
// ---------------------------------------------------------------------------
__global__ __launch_bounds__(256) void cvt_kernel(
    const float* __restrict__ x, bf16_t* __restrict__ y)
{
    int i = blockIdx.x * 256 + threadIdx.x;
    f32x4 v = ((const f32x4*)x)[i];
    bf16x4 o = { (bf16_t)v.x, (bf16_t)v.y, (bf16_t)v.z, (bf16_t)v.w };
    ((bf16x4*)y)[i] = o;
}

// ---------------------------------------------------------------------------
// 16-slice weight transpose+convert: W fp32 [K,N] -> Wt bf16 [N,K].
// ---------------------------------------------------------------------------
struct WT16 {
    const float* src[16]; bf16_t* dst[16];
    int srcN[16]; int dstK[16]; int k0b[16]; int n0b[16];
};

__global__ __launch_bounds__(256) void wt16_kernel(WT16 p)
{
    const int z = blockIdx.z;
    const float* W = p.src[z];
    bf16_t* Wt = p.dst[z];
    const int N = p.srcN[z], Kd = p.dstK[z];
    const int n0 = p.n0b[z] + blockIdx.x * 64, k0 = p.k0b[z] + blockIdx.y * 64;
    __shared__ float ts[64][65];
    const int tid = threadIdx.x;
#pragma unroll
    for (int it = 0; it < 4; ++it) {
        int f = tid + it * 256;
        int row = f >> 4, c4 = (f & 15) * 4;
        f32x4 v = *(const f32x4*)(W + (size_t)(k0 + row) * N + n0 + c4);
        ts[row][c4 + 0] = v.x; ts[row][c4 + 1] = v.y;
        ts[row][c4 + 2] = v.z; ts[row][c4 + 3] = v.w;
    }
    __syncthreads();
#pragma unroll
    for (int it = 0; it < 4; ++it) {
        int f = tid + it * 256;
        int nrow = f >> 4, k4 = (f & 15) * 4;
        bf16x4 o = { (bf16_t)ts[k4 + 0][nrow], (bf16_t)ts[k4 + 1][nrow],
                     (bf16_t)ts[k4 + 2][nrow], (bf16_t)ts[k4 + 3][nrow] };
        *(bf16x4*)(Wt + (size_t)(n0 + nrow) * Kd + k0 + k4) = o;
    }
}

// ---------------------------------------------------------------------------
// LayerNorm: fp32 in, bf16 out. One block per row of 1024.
// ---------------------------------------------------------------------------
__global__ __launch_bounds__(256) void ln_kernel(
    const float* __restrict__ x, const float* __restrict__ g,
    const float* __restrict__ b, bf16_t* __restrict__ y)
{
    const int row = blockIdx.x;
    const int tid = threadIdx.x;
    const f32x4* xr = (const f32x4*)(x + (size_t)row * 1024);
    f32x4 v = xr[tid];
    float s  = v.x + v.y + v.z + v.w;
    float s2 = v.x*v.x + v.y*v.y + v.z*v.z + v.w*v.w;
#pragma unroll
    for (int off = 1; off < 64; off <<= 1) {
        s  += __shfl_xor(s,  off, 64);
        s2 += __shfl_xor(s2, off, 64);
    }
    __shared__ float ws_[4], ws2_[4];
    const int wave = tid >> 6, lane = tid & 63;
    if (lane == 0) { ws_[wave] = s; ws2_[wave] = s2; }
    __syncthreads();
    s  = ws_[0] + ws_[1] + ws_[2] + ws_[3];
    s2 = ws2_[0] + ws2_[1] + ws2_[2] + ws2_[3];
    const float mu   = s  * (1.0f/1024.0f);
    const float var  = s2 * (1.0f/1024.0f) - mu*mu;
    const float rstd = rsqrtf(var + LN_EPS);
    f32x4 gv = ((const f32x4*)g)[tid];
    f32x4 bv = ((const f32x4*)b)[tid];
    f32x4 o  = (v - mu) * rstd * gv + bv;
    bf16x4 ob = { (bf16_t)o.x, (bf16_t)o.y, (bf16_t)o.z, (bf16_t)o.w };
    ((bf16x4*)(y + (size_t)row * 1024))[tid] = ob;
}

// ---------------------------------------------------------------------------
// bf16 MFMA GEMM. NBUF=2: Round-0 proven 2-buffer __syncthreads loop.
// NBUF=3 (R9): ring of 3 DEPTH-deep stages, SAME barrier count and SAME
// compute-per-barrier as NBUF=2, but counted vmcnt — the consumed stage was
// issued 2 iterations (~2000 cyc) before use, fully covering ~900 cyc
// HBM/L3 latency; vmcnt never drains to 0 in the main loop (T4, m218).
// Ring safety: one barrier per iteration; stage t+2 overwrites buf of stage
// t-1, consumed by ALL waves before barrier t (ds_reads complete before
// their MFMAs which precede the barrier in program order).
// LDS XOR swizzle (counter-verified 0 conflicts, free).
// out[M,N] = A[M,K] @ Bt[N,K]^T (+bias)(+relu)(+fp32 residual).
// XCD-aware swizzle (requires gridDim.y % 8 == 0).
// ---------------------------------------------------------------------------
template<int BN, int DEPTH, int NBUF, int OUT_BF16, int HAS_BIAS, int DO_RELU,
         int HAS_RES>
__global__ __launch_bounds__(256) void gemm_bf16(
    const bf16_t* __restrict__ A, const bf16_t* __restrict__ Bt,
    const float* __restrict__ bias, const float* __restrict__ res,
    void* __restrict__ out, int M, int N, int K)
{
    constexpr int NT = BN / 32;
    constexpr int L  = DEPTH * (2 + BN / 64);   // g2l16 per wave per stage
    __shared__ __align__(16) bf16_t As[NBUF][DEPTH][128 * 32];
    __shared__ __align__(16) bf16_t Bs[NBUF][DEPTH][BN * 32];

    const int tid  = threadIdx.x;
    const int wave = tid >> 6, lane = tid & 63;
    const int q    = lane >> 4, r = lane & 15;
    const int wm   = wave >> 1, wn = wave & 1;

    const int nbx  = gridDim.x;
    const int id   = blockIdx.y * nbx + blockIdx.x;
    const int mper = gridDim.y >> 3;
    const int jj   = id >> 3;
    const int bm   = (id & 7) * mper + jj / nbx;
    const int bn   = jj % nbx;
    const int m0   = bm * 128, n0 = bn * BN;

    const int srow = lane >> 2;                              // row in 16-row slab
    const int schk = ((lane & 3) ^ ((lane >> 3) & 3)) * 8;   // pre-swizzled src chunk
    const int rsw  = ((r >> 1) & 3) * 8;                     // read-side XOR

    auto stage = [&](int buf, int kk) {
#pragma unroll
        for (int s = 0; s < DEPTH; ++s) {
#pragma unroll
            for (int t = 0; t < 2; ++t) {
                int rowA = wave * 32 + t * 16;
                g2l16(A + (size_t)(m0 + rowA + srow) * K + kk + s * 32 + schk,
                      &As[buf][s][rowA * 32]);
            }
#pragma unroll
            for (int t = 0; t < BN / 64; ++t) {
                int rowB = wave * (BN / 4) + t * 16;
                g2l16(Bt + (size_t)(n0 + rowB + srow) * K + kk + s * 32 + schk,
                      &Bs[buf][s][rowB * 32]);
            }
        }
    };

    f32x4 acc[4][NT] = {};
    constexpr int STEP = 32 * DEPTH;

    auto compute = [&](int buf) {
#pragma unroll
        for (int s = 0; s < DEPTH; ++s) {
            bf16x8 af[4], bfr[NT];
#pragma unroll
            for (int i = 0; i < 4; ++i)
                af[i] = *(const bf16x8*)&As[buf][s][(wm * 64 + i * 16 + r) * 32 + (q * 8 ^ rsw)];
#pragma unroll
            for (int j = 0; j < NT; ++j)
                bfr[j] = *(const bf16x8*)&Bs[buf][s][(wn * 16 * NT + j * 16 + r) * 32 + (q * 8 ^ rsw)];
#pragma unroll
            for (int i = 0; i < 4; ++i)
#pragma unroll
                for (int j = 0; j < NT; ++j)
                    acc[i][j] = __builtin_amdgcn_mfma_f32_16x16x32_bf16(af[i], bfr[j], acc[i][j], 0, 0, 0);
        }
    };

    if constexpr (NBUF == 2) {
        stage(0, 0);
        for (int kk = 0; kk < K; kk += STEP) {
            const int cur = (kk / STEP) & 1;
            __syncthreads();
            if (kk + STEP < K) stage(cur ^ 1, kk + STEP);
            compute(cur);
        }
    } else {
        const int NK = K / STEP;
        stage(0, 0); stage(1, STEP);
        int t = 0;
        for (; t + 2 < NK; ++t) {
            wait_vm<L>();            // stage t landed; stage t+1 stays in flight
            block_bar();
            stage((t + 2) % NBUF, (t + 2) * STEP);
            compute(t % NBUF);
        }
        wait_vm<L>();  block_bar(); compute(t % NBUF); ++t;   // t = NK-2
        wait_vm<0>();  block_bar(); compute(t % NBUF);        // t = NK-1
    }

#pragma unroll
    for (int i = 0; i < 4; ++i)
#pragma unroll
        for (int j = 0; j < NT; ++j)
#pragma unroll
            for (int e = 0; e < 4; ++e) {
                int row = m0 + wm * 64 + i * 16 + q * 4 + e;
                int col = n0 + wn * 16 * NT + j * 16 + r;
                float v = acc[i][j][e];
                if (HAS_BIAS) v += bias[col];
                if (DO_RELU)  v = v > 0.0f ? v : 0.0f;
                if (HAS_RES)  v += res[(size_t)row * N + col];
                if (OUT_BF16) ((bf16_t*)out)[(size_t)row * N + col] = (bf16_t)v;
                else          ((float*)out)[(size_t)row * N + col] = v;
            }
}

// ---------------------------------------------------------------------------
// Grouped QKV projection GEMM (self & cross). N=3072, K=1024, M=4096, BN=128.
// Round-0 structure + zero-conflict swizzle (unchanged — R9 scope control).
// Group 0: A=Aq -> outq (scaled by 1/sqrt(D)); 1: A=Akv -> outk;
// 2: A=Akv -> vt (per-head transposed, bf16x4 packed).
// ---------------------------------------------------------------------------
__global__ __launch_bounds__(256) void gemm_qkv3(
    const bf16_t* __restrict__ Aq, const bf16_t* __restrict__ Akv,
    const bf16_t* __restrict__ Wt3,
    bf16_t* __restrict__ outq, bf16_t* __restrict__ outk,
    bf16_t* __restrict__ vt)
{
    const int K = 1024;
    __shared__ __align__(16) bf16_t As[2][128 * 32];
    __shared__ __align__(16) bf16_t Bs[2][128 * 32];

    const int tid  = threadIdx.x;
    const int wave = tid >> 6, lane = tid & 63;
    const int q    = lane >> 4, r = lane & 15;
    const int wm   = wave >> 1, wn = wave & 1;

    const int nbx  = gridDim.x;   // 24
    const int id   = blockIdx.y * nbx + blockIdx.x;
    const int mper = gridDim.y >> 3;
    const int jj   = id >> 3;
    const int bm   = (id & 7) * mper + jj / nbx;
    const int bn   = jj % nbx;
    const int m0   = bm * 128, n0 = bn * 128;
    const int grp  = bn >> 3;          // 0=q, 1=k, 2=v
    const bf16_t* A = (grp == 0) ? Aq : Akv;

    const int srow = lane >> 2;
    const int schk = ((lane & 3) ^ ((lane >> 3) & 3)) * 8;
    const int rsw  = ((r >> 1) & 3) * 8;

    auto stage = [&](int buf, int kk) {
#pragma unroll
        for (int t = 0; t < 2; ++t) {
            int row = wave * 32 + t * 16;
            g2l16(A   + (size_t)(m0 + row + srow) * K + kk + schk, &As[buf][row * 32]);
            g2l16(Wt3 + (size_t)(n0 + row + srow) * K + kk + schk, &Bs[buf][row * 32]);
        }
    };

    f32x4 acc[4][4] = {};
    stage(0, 0);

    for (int kk = 0; kk < K; kk += 32) {
        const int cur = (kk >> 5) & 1;
        __syncthreads();
        if (kk + 32 < K) stage(cur ^ 1, kk + 32);

        bf16x8 af[4], bfr[4];
#pragma unroll
        for (int i = 0; i < 4; ++i)
            af[i] = *(const bf16x8*)&As[cur][(wm * 64 + i * 16 + r) * 32 + (q * 8 ^ rsw)];
#pragma unroll
        for (int j = 0; j < 4; ++j)
            bfr[j] = *(const bf16x8*)&Bs[cur][(wn * 64 + j * 16 + r) * 32 + (q * 8 ^ rsw)];
#pragma unroll
        for (int i = 0; i < 4; ++i)
#pragma unroll
            for (int j = 0; j < 4; ++j)
                acc[i][j] = __builtin_amdgcn_mfma_f32_16x16x32_bf16(af[i], bfr[j], acc[i][j], 0, 0, 0);
    }

    if (grp < 2) {
        bf16_t* o = (grp == 0) ? outq : outk;
        const float sc = (grp == 0) ? 0.125f : 1.0f;   // 1/sqrt(64) folded into q
        const int c0 = n0 - grp * 1024;
#pragma unroll
        for (int i = 0; i < 4; ++i)
#pragma unroll
            for (int j = 0; j < 4; ++j)
#pragma unroll
                for (int e = 0; e < 4; ++e) {
                    int row = m0 + wm * 64 + i * 16 + q * 4 + e;
                    int col = c0 + wn * 64 + j * 16 + r;
                    o[(size_t)row * 1024 + col] = (bf16_t)(acc[i][j][e] * sc);
                }
    } else {
#pragma unroll
        for (int i = 0; i < 4; ++i)
#pragma unroll
            for (int j = 0; j < 4; ++j) {
                int c = (n0 - 2048) + wn * 64 + j * 16 + r;   // 0..1023
                int hh = c >> 6, d = c & 63;
                int row0 = m0 + wm * 64 + i * 16 + q * 4;
                int bb = row0 >> 10, t = row0 & 1023;
                bf16x4 pk = { (bf16_t)acc[i][j][0], (bf16_t)acc[i][j][1],
                              (bf16_t)acc[i][j][2], (bf16_t)acc[i][j][3] };
                *(bf16x4*)&vt[((size_t)((bb << 4) + hh) * 64 + d) * 1024 + t] = pk;
            }
    }
}

// ---------------------------------------------------------------------------
// MFMA flash attention (R3-proven staged structure; R8 pair-balanced causal
// schedule — both measured wins, unchanged this round).
// ---------------------------------------------------------------------------
template<int CAUSAL>
__global__ __launch_bounds__(256) void attn_mfma_kernel(
    const bf16_t* __restrict__ Qp, const bf16_t* __restrict__ Kp,
    const bf16_t* __restrict__ VTp, bf16_t* __restrict__ Op)
{
    const int T = 1024;
    const int LP = 72;
    __shared__ __align__(16) bf16_t Ps[128 * LP];        // Q staging then P
    __shared__ __align__(16) bf16_t Ks[2][2][64 * 32];   // [buf][ks]
    __shared__ __align__(16) bf16_t Vs[2][2][64 * 32];   // [buf][ks] rows=d

    const int id  = blockIdx.x + 8 * (blockIdx.y + 16 * blockIdx.z);
    int pr, qt;
    if (CAUSAL) {
        const int lo = id & 255;
        pr = lo >> 2;
        const int qp = lo & 3;
        qt = (id >= 256) ? (7 - qp) : qp;
    } else {
        const int jj = id >> 3;
        pr = (id & 7) * 8 + (jj >> 3);
        qt = jj & 7;
    }
    const int h   = pr & 15, b = pr >> 4;

    const int tid  = threadIdx.x;
    const int wave = tid >> 6, lane = tid & 63;
    const int q    = lane >> 4, r = lane & 15;
    const int srow = lane >> 2;
    const int schk = ((lane & 3) ^ ((lane >> 3) & 3)) * 8;   // pre-swizzled src chunk
    const int rsw  = ((r >> 1) & 3) * 8;                     // read-side XOR

    const bf16_t* Kb = Kp + (size_t)(b * T) * 1024 + h * 64;
    const bf16_t* Vb = VTp + (size_t)((b * 16 + h) * 64) * 1024;

    auto stageKV = [&](int buf, int kt) {
#pragma unroll
        for (int ks = 0; ks < 2; ++ks) {
            g2l16(Kb + (size_t)(kt * 64 + wave * 16 + srow) * 1024 + ks * 32 + schk,
                  &Ks[buf][ks][wave * 16 * 32]);
            g2l16(Vb + (size_t)(wave * 16 + srow) * 1024 + kt * 64 + ks * 32 + schk,
                  &Vs[buf][ks][wave * 16 * 32]);
        }
    };

    {   // stage Q tile (128 x 64 bf16) into Ps region
        const bf16_t* Qb = Qp + (size_t)(b * T + qt * 128) * 1024 + h * 64;
#pragma unroll
        for (int it = 0; it < 4; ++it) {
            int f = tid + it * 256;
            int row = f >> 3, c8 = (f & 7) * 8;
            *(bf16x8*)&Ps[row * LP + c8] = *(const bf16x8*)(Qb + (size_t)row * 1024 + c8);
        }
    }
    __syncthreads();
    bf16x8 qa[2][2];
#pragma unroll
    for (int mt = 0; mt < 2; ++mt)
#pragma unroll
        for (int ks = 0; ks < 2; ++ks)
            qa[mt][ks] = *(const bf16x8*)&Ps[(wave * 32 + mt * 16 + r) * LP + ks * 32 + q * 8];

    const bf16_t one_b = (bf16_t)1.0f;
    const bf16x8 ones = { one_b, one_b, one_b, one_b, one_b, one_b, one_b, one_b };

    f32x4 o[2][4] = {};
    f32x4 ol[2] = {};          // row-sums of P (l), same C-layout rows as o

    const int nk = CAUSAL ? (2 * qt + 2) : 16;
    stageKV(0, 0);

    for (int kt = 0; kt < nk; ++kt) {
        const int cur = kt & 1;
        __syncthreads();
        if (kt + 1 < nk) stageKV(cur ^ 1, kt + 1);

        // S = Q K^T (Q pre-scaled)
        f32x4 s[2][4] = {};
#pragma unroll
        for (int ks = 0; ks < 2; ++ks)
#pragma unroll
            for (int nt = 0; nt < 4; ++nt) {
                bf16x8 kb = *(const bf16x8*)&Ks[cur][ks][(nt * 16 + r) * 32 + (q * 8 ^ rsw)];
#pragma unroll
                for (int mt = 0; mt < 2; ++mt)
                    s[mt][nt] = __builtin_amdgcn_mfma_f32_16x16x32_bf16(qa[mt][ks], kb, s[mt][nt], 0, 0, 0);
            }

        if (CAUSAL) {
#pragma unroll
            for (int mt = 0; mt < 2; ++mt) {
                const int r0 = qt * 128 + wave * 32 + mt * 16;
                if (kt * 64 + 63 > r0) {
#pragma unroll
                    for (int nt = 0; nt < 4; ++nt) {
                        int kg = kt * 64 + nt * 16 + r;
#pragma unroll
                        for (int i2 = 0; i2 < 4; ++i2)
                            if (kg > r0 + q * 4 + i2) s[mt][nt][i2] = -INFINITY;
                    }
                }
            }
        }

        // P = exp(S); write to LDS (own rows only -> no barrier needed)
#pragma unroll
        for (int mt = 0; mt < 2; ++mt)
#pragma unroll
            for (int nt = 0; nt < 4; ++nt)
#pragma unroll
                for (int i2 = 0; i2 < 4; ++i2)
                    Ps[(wave * 32 + mt * 16 + q * 4 + i2) * LP + nt * 16 + r] =
                        (bf16_t)__expf(s[mt][nt][i2]);

        // O += P V ; l += P . 1
#pragma unroll
        for (int ks = 0; ks < 2; ++ks) {
            bf16x8 pa[2];
#pragma unroll
            for (int mt = 0; mt < 2; ++mt)
                pa[mt] = *(const bf16x8*)&Ps[(wave * 32 + mt * 16 + r) * LP + ks * 32 + q * 8];
#pragma unroll
            for (int dt = 0; dt < 4; ++dt) {
                bf16x8 vb = *(const bf16x8*)&Vs[cur][ks][(dt * 16 + r) * 32 + (q * 8 ^ rsw)];
#pragma unroll
                for (int mt = 0; mt < 2; ++mt)
                    o[mt][dt] = __builtin_amdgcn_mfma_f32_16x16x32_bf16(pa[mt], vb, o[mt][dt], 0, 0, 0);
            }
#pragma unroll
            for (int mt = 0; mt < 2; ++mt)
                ol[mt] = __builtin_amdgcn_mfma_f32_16x16x32_bf16(pa[mt], ones, ol[mt], 0, 0, 0);
        }
    }

    bf16_t* Ob = Op + (size_t)(b * T + qt * 128 + wave * 32) * 1024 + h * 64;
#pragma unroll
    for (int mt = 0; mt < 2; ++mt) {
        f32x4 inv;
#pragma unroll
        for (int i2 = 0; i2 < 4; ++i2) inv[i2] = 1.0f / ol[mt][i2];
#pragma unroll
        for (int dt = 0; dt < 4; ++dt)
#pragma unroll
            for (int i2 = 0; i2 < 4; ++i2)
                Ob[(size_t)(mt * 16 + q * 4 + i2) * 1024 + dt * 16 + r] = (bf16_t)(o[mt][dt][i2] * inv[i2]);
    }
}

// ---------------------------------------------------------------------------
extern "C" void kernel_launch(void* const* d_in, const int* in_sizes, int n_in,
                              void* d_out, int out_size, void* d_ws, size_t ws_size,
                              hipStream_t stream)
{
    const float* x     = (const float*)d_in[0];
    const float* enc   = (const float*)d_in[1];
    const float* sa_wq = (const float*)d_in[2];
    const float* sa_wk = (const float*)d_in[3];
    const float* sa_wv = (const float*)d_in[4];
    const float* sa_wo = (const float*)d_in[5];
    const float* sa_bo = (const float*)d_in[6];
    const float* ca_wq = (const float*)d_in[7];
    const float* ca_wk = (const float*)d_in[8];
    const float* ca_wv = (const float*)d_in[9];
    const float* ca_wo = (const float*)d_in[10];
    const float* ca_bo = (const float*)d_in[11];
    const float* ff_w1 = (const float*)d_in[12];
    const float* ff_b1 = (const float*)d_in[13];
    const float* ff_w2 = (const float*)d_in[14];
    const float* ff_b2 = (const float*)d_in[15];
    const float* ln1_g = (const float*)d_in[16];
    const float* ln1_b = (const float*)d_in[17];
    const float* ln2_g = (const float*)d_in[18];
    const float* ln2_b = (const float*)d_in[19];
    const float* ln3_g = (const float*)d_in[20];
    const float* ln3_b = (const float*)d_in[21];

    float* out = (float*)d_out;
    char* ws = (char*)d_ws;
    const size_t MB = 1024 * 1024;
    bf16_t* w_s3  = (bf16_t*)(ws +  0 * MB);   // self  [3072][1024] 6 MB (q|k|v)
    bf16_t* w_so  = (bf16_t*)(ws +  6 * MB);   // 2 MB
    bf16_t* w_c3  = (bf16_t*)(ws +  8 * MB);   // cross [3072][1024] 6 MB (q|k|v)
    bf16_t* w_co  = (bf16_t*)(ws + 14 * MB);   // 2 MB
    bf16_t* w_f1  = (bf16_t*)(ws + 16 * MB);   // [4096][1024] 8 MB
    bf16_t* w_f2  = (bf16_t*)(ws + 24 * MB);   // [1024][4096] 8 MB
    bf16_t* b_enc = (bf16_t*)(ws + 32 * MB);   // 8 MB
    bf16_t* b_ln  = (bf16_t*)(ws + 40 * MB);   // 8 MB
    bf16_t* b_q   = (bf16_t*)(ws + 48 * MB);   // [4096][1024] 8 MB
    bf16_t* b_k   = (bf16_t*)(ws + 56 * MB);   // [4096][1024] 8 MB
    bf16_t* b_vt  = (bf16_t*)(ws + 64 * MB);   // [4096(b,h,d)][1024] 8 MB
    bf16_t* b_at  = (bf16_t*)(ws + 72 * MB);   // [4096][1024] 8 MB
    float*  b_x1  = (float*) (ws + 80 * MB);   // fp32, 16 MB
    float*  b_x2  = (float*) (ws + 48 * MB);   // fp32, over b_q/b_k (dead)
    bf16_t* b_h1  = (bf16_t*)(ws + 64 * MB);   // [4096][4096] 32 MB (vt/at/x1 dead)

    const int M = 4096;  // B*T
    dim3 blk(256);

    // --- pre-pass: all weights -> bf16 [N,K] in ONE launch; enc -> bf16 ---
    WT16 wp;
    const float* srcs[8] = { sa_wq, sa_wk, sa_wv, sa_wo, ca_wq, ca_wk, ca_wv, ca_wo };
    bf16_t* dsts[8] = { w_s3, w_s3 + 1024*1024, w_s3 + 2048*1024, w_so,
                        w_c3, w_c3 + 1024*1024, w_c3 + 2048*1024, w_co };
    for (int z = 0; z < 8; ++z) {
        wp.src[z] = srcs[z]; wp.dst[z] = dsts[z];
        wp.srcN[z] = 1024; wp.dstK[z] = 1024; wp.k0b[z] = 0; wp.n0b[z] = 0;
    }
    for (int z = 8; z < 12; ++z) {   // ff_w1 [1024][4096] -> [4096][1024]
        wp.src[z] = ff_w1; wp.dst[z] = w_f1;
        wp.srcN[z] = 4096; wp.dstK[z] = 1024; wp.k0b[z] = 0; wp.n0b[z] = (z - 8) * 1024;
    }
    for (int z = 12; z < 16; ++z) {  // ff_w2 [4096][1024] -> [1024][4096]
        wp.src[z] = ff_w2; wp.dst[z] = w_f2;
        wp.srcN[z] = 1024; wp.dstK[z] = 4096; wp.k0b[z] = (z - 12) * 1024; wp.n0b[z] = 0;
    }
    wt16_kernel<<<dim3(16, 16, 16), blk, 0, stream>>>(wp);
    cvt_kernel<<<4096, blk, 0, stream>>>(enc, b_enc);

    // 1) ln1(x)
    ln_kernel<<<4096, blk, 0, stream>>>(x, ln1_g, ln1_b, b_ln);
    // 2) fused self QKV -> q (scaled), k row-major + v transposed
    gemm_qkv3<<<dim3(24, 32), blk, 0, stream>>>(b_ln, b_ln, w_s3, b_q, b_k, b_vt);
    // 3) causal self-attention (pair-balanced schedule: qt & 7-qt same CU)
    attn_mfma_kernel<1><<<dim3(8, 16, 4), blk, 0, stream>>>(b_q, b_k, b_vt, b_at);
    // 4) out-proj + bias + residual(x) -> x1 (fp32), NBUF=3 ring
    gemm_bf16<64,2,3,0,1,0,1><<<dim3(16, 32), blk, 0, stream>>>(
        b_at, w_so, sa_bo, x, b_x1, M, 1024, 1024);
    // 5) ln2(x1)
    ln_kernel<<<4096, blk, 0, stream>>>(b_x1, ln2_g, ln2_b, b_ln);
    // 6) fused cross projections: q from ln2(x1), k/v from encoder_out
    gemm_qkv3<<<dim3(24, 32), blk, 0, stream>>>(b_ln, b_enc, w_c3, b_q, b_k, b_vt);
    // 7) full cross-attention (XCD-swizzled, balanced by nature)
    attn_mfma_kernel<0><<<dim3(8, 16, 4), blk, 0, stream>>>(b_q, b_k, b_vt, b_at);
    // 8) out-proj + bias + residual(x1) -> x2 (fp32), NBUF=3 ring
    gemm_bf16<64,2,3,0,1,0,1><<<dim3(16, 32), blk, 0, stream>>>(
        b_at, w_co, ca_bo, b_x1, b_x2, M, 1024, 1024);
    // 9) ln3(x2)
    ln_kernel<<<4096, blk, 0, stream>>>(b_x2, ln3_g, ln3_b, b_ln);
    // 10) FFN up: relu(ln3 @ w1 + b1) -> h1 (bf16) — NBUF=2 (keeps 4 blk/CU)
    gemm_bf16<128,1,2,1,1,1,0><<<dim3(32, 32), blk, 0, stream>>>(
        b_ln, w_f1, ff_b1, nullptr, b_h1, M, 4096, 1024);
    // 11) FFN down + bias + residual(x2) -> out — NBUF=3 ring (R9 test:
    //     same 64 barriers & compute/barrier as R0, cover 2 iterations)
    gemm_bf16<64,2,3,0,1,0,1><<<dim3(16, 32), blk, 0, stream>>>(
        b_h1, w_f2, ff_b2, b_x2, out, M, 1024, 4096);
}

// Round 10
// 465.071 us; speedup vs baseline: 1.0713x; 1.0713x over previous
//
#include <hip/hip_runtime.h>

typedef __bf16 bf16_t;
typedef __bf16 bf16x4 __attribute__((ext_vector_type(4)));
typedef __bf16 bf16x8 __attribute__((ext_vector_type(8)));
typedef float  f32x4  __attribute__((ext_vector_type(4)));

#define LN_EPS 1e-5f

__device__ __forceinline__ void g2l16(const bf16_t* g, bf16_t* l) {
    __builtin_amdgcn_global_load_lds(
        (const __attribute__((address_space(1))) void*)g,
        (__attribute__((address_space(3))) void*)l, 16, 0, 0);
}

// ---------------------------------------------------------------------------
// fp32 -> bf16 elementwise convert (n multiple of 1024).
// ---------------------------------------------------------------------------
__global__ __launch_bounds__(256) void cvt_kernel(
    const float* __restrict__ x, bf16_t* __restrict__ y)
{
    int i = blockIdx.x * 256 + threadIdx.x;
    f32x4 v = ((const f32x4*)x)[i];
    bf16x4 o = { (bf16_t)v.x, (bf16_t)v.y, (bf16_t)v.z, (bf16_t)v.w };
    ((bf16x4*)y)[i] = o;
}

// ---------------------------------------------------------------------------
// 16-slice weight transpose+convert: W fp32 [K,N] -> Wt bf16 [N,K].
// ---------------------------------------------------------------------------
struct WT16 {
    const float* src[16]; bf16_t* dst[16];
    int srcN[16]; int dstK[16]; int k0b[16]; int n0b[16];
};

__global__ __launch_bounds__(256) void wt16_kernel(WT16 p)
{
    const int z = blockIdx.z;
    const float* W = p.src[z];
    bf16_t* Wt = p.dst[z];
    const int N = p.srcN[z], Kd = p.dstK[z];
    const int n0 = p.n0b[z] + blockIdx.x * 64, k0 = p.k0b[z] + blockIdx.y * 64;
    __shared__ float ts[64][65];
    const int tid = threadIdx.x;
#pragma unroll
    for (int it = 0; it < 4; ++it) {
        int f = tid + it * 256;
        int row = f >> 4, c4 = (f & 15) * 4;
        f32x4 v = *(const f32x4*)(W + (size_t)(k0 + row) * N + n0 + c4);
        ts[row][c4 + 0] = v.x; ts[row][c4 + 1] = v.y;
        ts[row][c4 + 2] = v.z; ts[row][c4 + 3] = v.w;
    }
    __syncthreads();
#pragma unroll
    for (int it = 0; it < 4; ++it) {
        int f = tid + it * 256;
        int nrow = f >> 4, k4 = (f & 15) * 4;
        bf16x4 o = { (bf16_t)ts[k4 + 0][nrow], (bf16_t)ts[k4 + 1][nrow],
                     (bf16_t)ts[k4 + 2][nrow], (bf16_t)ts[k4 + 3][nrow] };
        *(bf16x4*)(Wt + (size_t)(n0 + nrow) * Kd + k0 + k4) = o;
    }
}

// ---------------------------------------------------------------------------
// LayerNorm: fp32 in, bf16 out. One block per row of 1024.
// ---------------------------------------------------------------------------
__global__ __launch_bounds__(256) void ln_kernel(
    const float* __restrict__ x, const float* __restrict__ g,
    const float* __restrict__ b, bf16_t* __restrict__ y)
{
    const int row = blockIdx.x;
    const int tid = threadIdx.x;
    const f32x4* xr = (const f32x4*)(x + (size_t)row * 1024);
    f32x4 v = xr[tid];
    float s  = v.x + v.y + v.z + v.w;
    float s2 = v.x*v.x + v.y*v.y + v.z*v.z + v.w*v.w;
#pragma unroll
    for (int off = 1; off < 64; off <<= 1) {
        s  += __shfl_xor(s,  off, 64);
        s2 += __shfl_xor(s2, off, 64);
    }
    __shared__ float ws_[4], ws2_[4];
    const int wave = tid >> 6, lane = tid & 63;
    if (lane == 0) { ws_[wave] = s; ws2_[wave] = s2; }
    __syncthreads();
    s  = ws_[0] + ws_[1] + ws_[2] + ws_[3];
    s2 = ws2_[0] + ws2_[1] + ws2_[2] + ws2_[3];
    const float mu   = s  * (1.0f/1024.0f);
    const float var  = s2 * (1.0f/1024.0f) - mu*mu;
    const float rstd = rsqrtf(var + LN_EPS);
    f32x4 gv = ((const f32x4*)g)[tid];
    f32x4 bv = ((const f32x4*)b)[tid];
    f32x4 o  = (v - mu) * rstd * gv + bv;
    bf16x4 ob = { (bf16_t)o.x, (bf16_t)o.y, (bf16_t)o.z, (bf16_t)o.w };
    ((bf16x4*)(y + (size_t)row * 1024))[tid] = ob;
}

// ---------------------------------------------------------------------------
// bf16 MFMA GEMM, double-buffered g2l16 pipeline with DEPTH k-slabs per
// barrier (Round-0 proven structure; R1/R9 measured counted-vmcnt rings are
// regressions on this 4-wave template — regime-gated, needs 8-phase).
// LDS bank-conflict-free XOR swizzle (counter-verified 0 conflicts, free).
// out[M,N] = A[M,K] @ Bt[N,K]^T (+bias)(+relu)(+fp32 residual).
// XCD-aware swizzle (requires gridDim.y % 8 == 0).
// ---------------------------------------------------------------------------
template<int BN, int DEPTH, int OUT_BF16, int HAS_BIAS, int DO_RELU, int HAS_RES>
__global__ __launch_bounds__(256) void gemm_bf16(
    const bf16_t* __restrict__ A, const bf16_t* __restrict__ Bt,
    const float* __restrict__ bias, const float* __restrict__ res,
    void* __restrict__ out, int M, int N, int K)
{
    constexpr int NT = BN / 32;
    __shared__ __align__(16) bf16_t As[2][DEPTH][128 * 32];
    __shared__ __align__(16) bf16_t Bs[2][DEPTH][BN * 32];

    const int tid  = threadIdx.x;
    const int wave = tid >> 6, lane = tid & 63;
    const int q    = lane >> 4, r = lane & 15;
    const int wm   = wave >> 1, wn = wave & 1;

    const int nbx  = gridDim.x;
    const int id   = blockIdx.y * nbx + blockIdx.x;
    const int mper = gridDim.y >> 3;
    const int jj   = id >> 3;
    const int bm   = (id & 7) * mper + jj / nbx;
    const int bn   = jj % nbx;
    const int m0   = bm * 128, n0 = bn * BN;

    const int srow = lane >> 2;                              // row in 16-row slab
    const int schk = ((lane & 3) ^ ((lane >> 3) & 3)) * 8;   // pre-swizzled src chunk
    const int rsw  = ((r >> 1) & 3) * 8;                     // read-side XOR

    auto stage = [&](int buf, int kk) {
#pragma unroll
        for (int s = 0; s < DEPTH; ++s) {
#pragma unroll
            for (int t = 0; t < 2; ++t) {
                int rowA = wave * 32 + t * 16;
                g2l16(A + (size_t)(m0 + rowA + srow) * K + kk + s * 32 + schk,
                      &As[buf][s][rowA * 32]);
            }
#pragma unroll
            for (int t = 0; t < BN / 64; ++t) {
                int rowB = wave * (BN / 4) + t * 16;
                g2l16(Bt + (size_t)(n0 + rowB + srow) * K + kk + s * 32 + schk,
                      &Bs[buf][s][rowB * 32]);
            }
        }
    };

    f32x4 acc[4][NT] = {};
    constexpr int STEP = 32 * DEPTH;
    stage(0, 0);

    for (int kk = 0; kk < K; kk += STEP) {
        const int cur = (kk / STEP) & 1;
        __syncthreads();
        if (kk + STEP < K) stage(cur ^ 1, kk + STEP);
#pragma unroll
        for (int s = 0; s < DEPTH; ++s) {
            bf16x8 af[4], bfr[NT];
#pragma unroll
            for (int i = 0; i < 4; ++i)
                af[i] = *(const bf16x8*)&As[cur][s][(wm * 64 + i * 16 + r) * 32 + (q * 8 ^ rsw)];
#pragma unroll
            for (int j = 0; j < NT; ++j)
                bfr[j] = *(const bf16x8*)&Bs[cur][s][(wn * 16 * NT + j * 16 + r) * 32 + (q * 8 ^ rsw)];
#pragma unroll
            for (int i = 0; i < 4; ++i)
#pragma unroll
                for (int j = 0; j < NT; ++j)
                    acc[i][j] = __builtin_amdgcn_mfma_f32_16x16x32_bf16(af[i], bfr[j], acc[i][j], 0, 0, 0);
        }
    }

#pragma unroll
    for (int i = 0; i < 4; ++i)
#pragma unroll
        for (int j = 0; j < NT; ++j)
#pragma unroll
            for (int e = 0; e < 4; ++e) {
                int row = m0 + wm * 64 + i * 16 + q * 4 + e;
                int col = n0 + wn * 16 * NT + j * 16 + r;
                float v = acc[i][j][e];
                if (HAS_BIAS) v += bias[col];
                if (DO_RELU)  v = v > 0.0f ? v : 0.0f;
                if (HAS_RES)  v += res[(size_t)row * N + col];
                if (OUT_BF16) ((bf16_t*)out)[(size_t)row * N + col] = (bf16_t)v;
                else          ((float*)out)[(size_t)row * N + col] = v;
            }
}

// ---------------------------------------------------------------------------
// 256x256 8-phase GEMM (T2+T3+T4+T5 combo, m201 geometry) for shapes with
// grid >= 256 blocks: out[M,N] = relu(A[M,K] @ Bt[N,K]^T + bias), bf16 out.
// 512 threads = 8 waves (2M x 4N); BK=64; LDS 128 KB [dbuf][A/B][half][128*64].
// Per K-tile 4 phases, quadrant (hA,hB) = (0,0),(0,1),(1,0),(1,1):
//   {12 ds_read_b128 | stage 1 half of tile kt+1 (2 g2l16) -> counted vmcnt
//    -> s_barrier -> setprio(1) + 16 MFMA + setprio(0) -> s_barrier}
// Stage order [A0,B0,B1,A1]; first-use A0,B0@p0, B1@p1, A1@p2 => vmcnt
// ladder [4,4,6,4] (never drains to 0 in the main loop). Staging always
// targets the OTHER buffer (1 tile ahead) => no WAR hazard (barrier skew <1
// interval). Swizzle byte^=(row&7)<<4, both-sides: per-lane pre-swizzled
// GLOBAL source + linear wave-uniform g2l16 dest (m104) + swizzled ds_read.
// ---------------------------------------------------------------------------
__global__ __launch_bounds__(512) void gemm_256(
    const bf16_t* __restrict__ A, const bf16_t* __restrict__ Bt,
    const float* __restrict__ bias, bf16_t* __restrict__ out,
    int M, int N, int K)
{
    __shared__ __align__(16) bf16_t lds[2][2][2][128 * 64];  // [buf][op][half]

    const int tid  = threadIdx.x;
    const int wave = tid >> 6, lane = tid & 63;
    const int q    = lane >> 4, r = lane & 15;
    const int wm   = wave >> 2, wn = wave & 3;

    // XCD swizzle: 8 XCDs, grid 256 -> 32 blocks/XCD, 2 A-panels per XCD.
    const int id  = blockIdx.y * gridDim.x + blockIdx.x;
    const int sid = (id & 7) * 32 + (id >> 3);
    const int bm  = sid >> 4, bn = sid & 15;
    const int m0  = bm * 256, n0 = bn * 256;

    // staging source (per-lane, pre-swizzled) + wave-uniform LDS dest
    int srow[2], selem[2];
#pragma unroll
    for (int l = 0; l < 2; ++l) {
        int o  = (wave * 64 + lane) * 16 + l * 8192;   // linear byte in half-tile
        int lo = o ^ (((o >> 7) & 7) << 4);            // logical (involution)
        srow[l]  = lo >> 7;
        selem[l] = (lo & 127) >> 1;
    }
    const int sd0 = wave * 512;                        // bf16 units, wave-uniform

    auto stageA = [&](int buf, int h, int kt) {
#pragma unroll
        for (int l = 0; l < 2; ++l)
            g2l16(A + (size_t)(m0 + h * 128 + srow[l]) * K + kt * 64 + selem[l],
                  &lds[buf][0][h][sd0 + l * 4096]);
    };
    auto stageB = [&](int buf, int h, int kt) {
#pragma unroll
        for (int l = 0; l < 2; ++l)
            g2l16(Bt + (size_t)(n0 + h * 128 + srow[l]) * K + kt * 64 + selem[l],
                  &lds[buf][1][h][sd0 + l * 4096]);
    };

    // ds_read fragment offsets (swizzled), loop-invariant
    int aoff[4][2], boff[2][2];
#pragma unroll
    for (int i = 0; i < 4; ++i) {
        int row = wm * 64 + i * 16 + r;
#pragma unroll
        for (int ks = 0; ks < 2; ++ks) {
            int colB = ks * 64 + q * 16;
            aoff[i][ks] = (row * 128 + (colB ^ ((row & 7) << 4))) >> 1;
        }
    }
#pragma unroll
    for (int j = 0; j < 2; ++j) {
        int row = wn * 32 + j * 16 + r;
#pragma unroll
        for (int ks = 0; ks < 2; ++ks) {
            int colB = ks * 64 + q * 16;
            boff[j][ks] = (row * 128 + (colB ^ ((row & 7) << 4))) >> 1;
        }
    }

    f32x4 acc[2][2][4][2] = {};

    // prologue: tile 0 fully staged, drained once (outside main loop)
    stageA(0, 0, 0); stageB(0, 0, 0); stageB(0, 1, 0); stageA(0, 1, 0);
    asm volatile("s_waitcnt vmcnt(0)" ::: "memory");
    __builtin_amdgcn_s_barrier();
    asm volatile("" ::: "memory");

    const int NTk = K >> 6;

#define QPHASE(HA, HB, STMT_STAGE, VMC_ST, VMC_LAST)                           \
    {                                                                          \
        bf16x8 af[4][2], bfr[2][2];                                            \
        _Pragma("unroll") for (int i = 0; i < 4; ++i)                          \
        _Pragma("unroll") for (int ks = 0; ks < 2; ++ks)                       \
            af[i][ks] = *(const bf16x8*)&lds[buf][0][HA][aoff[i][ks]];         \
        _Pragma("unroll") for (int j = 0; j < 2; ++j)                          \
        _Pragma("unroll") for (int ks = 0; ks < 2; ++ks)                       \
            bfr[j][ks] = *(const bf16x8*)&lds[buf][1][HB][boff[j][ks]];        \
        if (st) { STMT_STAGE;                                                  \
                  asm volatile("s_waitcnt vmcnt(" #VMC_ST ")" ::: "memory"); } \
        else    { asm volatile("s_waitcnt vmcnt(" #VMC_LAST ")" ::: "memory");}\
        __builtin_amdgcn_s_barrier();                                          \
        asm volatile("" ::: "memory");                                         \
        __builtin_amdgcn_s_setprio(1);                                         \
        _Pragma("unroll") for (int i = 0; i < 4; ++i)                          \
        _Pragma("unroll") for (int j = 0; j < 2; ++j)                          \
        _Pragma("unroll") for (int ks = 0; ks < 2; ++ks)                       \
            acc[HA][HB][i][j] = __builtin_amdgcn_mfma_f32_16x16x32_bf16(       \
                af[i][ks], bfr[j][ks], acc[HA][HB][i][j], 0, 0, 0);            \
        __builtin_amdgcn_s_setprio(0);                                         \
        __builtin_amdgcn_s_barrier();                                          \
        asm volatile("" ::: "memory");                                         \
    }

    for (int kt = 0; kt < NTk; ++kt) {
        const int buf = kt & 1, nbuf = buf ^ 1;
        const bool st = (kt + 1 < NTk);
        QPHASE(0, 0, stageA(nbuf, 0, kt + 1), 4, 2)
        QPHASE(0, 1, stageB(nbuf, 0, kt + 1), 4, 0)
        QPHASE(1, 0, stageB(nbuf, 1, kt + 1), 6, 6)
        QPHASE(1, 1, stageA(nbuf, 1, kt + 1), 4, 6)
    }
#undef QPHASE

    // epilogue: bias + relu + bf16 store
#pragma unroll
    for (int hA = 0; hA < 2; ++hA)
#pragma unroll
    for (int hB = 0; hB < 2; ++hB)
#pragma unroll
    for (int i = 0; i < 4; ++i)
#pragma unroll
    for (int j = 0; j < 2; ++j)
#pragma unroll
    for (int e = 0; e < 4; ++e) {
        int row = m0 + hA * 128 + wm * 64 + i * 16 + q * 4 + e;
        int col = n0 + hB * 128 + wn * 32 + j * 16 + r;
        float v = acc[hA][hB][i][j][e] + bias[col];
        v = v > 0.0f ? v : 0.0f;
        out[(size_t)row * N + col] = (bf16_t)v;
    }
}

// ---------------------------------------------------------------------------
// Grouped QKV projection GEMM (self & cross). N=3072, K=1024, M=4096, BN=128.
// Round-0 structure + zero-conflict swizzle.
// Group 0: A=Aq -> outq (scaled by 1/sqrt(D)); 1: A=Akv -> outk;
// 2: A=Akv -> vt (per-head transposed, bf16x4 packed).
// ---------------------------------------------------------------------------
__global__ __launch_bounds__(256) void gemm_qkv3(
    const bf16_t* __restrict__ Aq, const bf16_t* __restrict__ Akv,
    const bf16_t* __restrict__ Wt3,
    bf16_t* __restrict__ outq, bf16_t* __restrict__ outk,
    bf16_t* __restrict__ vt)
{
    const int K = 1024;
    __shared__ __align__(16) bf16_t As[2][128 * 32];
    __shared__ __align__(16) bf16_t Bs[2][128 * 32];

    const int tid  = threadIdx.x;
    const int wave = tid >> 6, lane = tid & 63;
    const int q    = lane >> 4, r = lane & 15;
    const int wm   = wave >> 1, wn = wave & 1;

    const int nbx  = gridDim.x;   // 24
    const int id   = blockIdx.y * nbx + blockIdx.x;
    const int mper = gridDim.y >> 3;
    const int jj   = id >> 3;
    const int bm   = (id & 7) * mper + jj / nbx;
    const int bn   = jj % nbx;
    const int m0   = bm * 128, n0 = bn * 128;
    const int grp  = bn >> 3;          // 0=q, 1=k, 2=v
    const bf16_t* A = (grp == 0) ? Aq : Akv;

    const int srow = lane >> 2;
    const int schk = ((lane & 3) ^ ((lane >> 3) & 3)) * 8;
    const int rsw  = ((r >> 1) & 3) * 8;

    auto stage = [&](int buf, int kk) {
#pragma unroll
        for (int t = 0; t < 2; ++t) {
            int row = wave * 32 + t * 16;
            g2l16(A   + (size_t)(m0 + row + srow) * K + kk + schk, &As[buf][row * 32]);
            g2l16(Wt3 + (size_t)(n0 + row + srow) * K + kk + schk, &Bs[buf][row * 32]);
        }
    };

    f32x4 acc[4][4] = {};
    stage(0, 0);

    for (int kk = 0; kk < K; kk += 32) {
        const int cur = (kk >> 5) & 1;
        __syncthreads();
        if (kk + 32 < K) stage(cur ^ 1, kk + 32);

        bf16x8 af[4], bfr[4];
#pragma unroll
        for (int i = 0; i < 4; ++i)
            af[i] = *(const bf16x8*)&As[cur][(wm * 64 + i * 16 + r) * 32 + (q * 8 ^ rsw)];
#pragma unroll
        for (int j = 0; j < 4; ++j)
            bfr[j] = *(const bf16x8*)&Bs[cur][(wn * 64 + j * 16 + r) * 32 + (q * 8 ^ rsw)];
#pragma unroll
        for (int i = 0; i < 4; ++i)
#pragma unroll
            for (int j = 0; j < 4; ++j)
                acc[i][j] = __builtin_amdgcn_mfma_f32_16x16x32_bf16(af[i], bfr[j], acc[i][j], 0, 0, 0);
    }

    if (grp < 2) {
        bf16_t* o = (grp == 0) ? outq : outk;
        const float sc = (grp == 0) ? 0.125f : 1.0f;   // 1/sqrt(64) folded into q
        const int c0 = n0 - grp * 1024;
#pragma unroll
        for (int i = 0; i < 4; ++i)
#pragma unroll
            for (int j = 0; j < 4; ++j)
#pragma unroll
                for (int e = 0; e < 4; ++e) {
                    int row = m0 + wm * 64 + i * 16 + q * 4 + e;
                    int col = c0 + wn * 64 + j * 16 + r;
                    o[(size_t)row * 1024 + col] = (bf16_t)(acc[i][j][e] * sc);
                }
    } else {
#pragma unroll
        for (int i = 0; i < 4; ++i)
#pragma unroll
            for (int j = 0; j < 4; ++j) {
                int c = (n0 - 2048) + wn * 64 + j * 16 + r;   // 0..1023
                int hh = c >> 6, d = c & 63;
                int row0 = m0 + wm * 64 + i * 16 + q * 4;
                int bb = row0 >> 10, t = row0 & 1023;
                bf16x4 pk = { (bf16_t)acc[i][j][0], (bf16_t)acc[i][j][1],
                              (bf16_t)acc[i][j][2], (bf16_t)acc[i][j][3] };
                *(bf16x4*)&vt[((size_t)((bb << 4) + hh) * 64 + d) * 1024 + t] = pk;
            }
    }
}

// ---------------------------------------------------------------------------
// MFMA flash attention (R3-proven staged structure; R8 pair-balanced causal
// schedule — both measured wins, unchanged).
// ---------------------------------------------------------------------------
template<int CAUSAL>
__global__ __launch_bounds__(256) void attn_mfma_kernel(
    const bf16_t* __restrict__ Qp, const bf16_t* __restrict__ Kp,
    const bf16_t* __restrict__ VTp, bf16_t* __restrict__ Op)
{
    const int T = 1024;
    const int LP = 72;
    __shared__ __align__(16) bf16_t Ps[128 * LP];        // Q staging then P
    __shared__ __align__(16) bf16_t Ks[2][2][64 * 32];   // [buf][ks]
    __shared__ __align__(16) bf16_t Vs[2][2][64 * 32];   // [buf][ks] rows=d

    const int id  = blockIdx.x + 8 * (blockIdx.y + 16 * blockIdx.z);
    int pr, qt;
    if (CAUSAL) {
        const int lo = id & 255;
        pr = lo >> 2;
        const int qp = lo & 3;
        qt = (id >= 256) ? (7 - qp) : qp;
    } else {
        const int jj = id >> 3;
        pr = (id & 7) * 8 + (jj >> 3);
        qt = jj & 7;
    }
    const int h   = pr & 15, b = pr >> 4;

    const int tid  = threadIdx.x;
    const int wave = tid >> 6, lane = tid & 63;
    const int q    = lane >> 4, r = lane & 15;
    const int srow = lane >> 2;
    const int schk = ((lane & 3) ^ ((lane >> 3) & 3)) * 8;   // pre-swizzled src chunk
    const int rsw  = ((r >> 1) & 3) * 8;                     // read-side XOR

    const bf16_t* Kb = Kp + (size_t)(b * T) * 1024 + h * 64;
    const bf16_t* Vb = VTp + (size_t)((b * 16 + h) * 64) * 1024;

    auto stageKV = [&](int buf, int kt) {
#pragma unroll
        for (int ks = 0; ks < 2; ++ks) {
            g2l16(Kb + (size_t)(kt * 64 + wave * 16 + srow) * 1024 + ks * 32 + schk,
                  &Ks[buf][ks][wave * 16 * 32]);
            g2l16(Vb + (size_t)(wave * 16 + srow) * 1024 + kt * 64 + ks * 32 + schk,
                  &Vs[buf][ks][wave * 16 * 32]);
        }
    };

    {   // stage Q tile (128 x 64 bf16) into Ps region
        const bf16_t* Qb = Qp + (size_t)(b * T + qt * 128) * 1024 + h * 64;
#pragma unroll
        for (int it = 0; it < 4; ++it) {
            int f = tid + it * 256;
            int row = f >> 3, c8 = (f & 7) * 8;
            *(bf16x8*)&Ps[row * LP + c8] = *(const bf16x8*)(Qb + (size_t)row * 1024 + c8);
        }
    }
    __syncthreads();
    bf16x8 qa[2][2];
#pragma unroll
    for (int mt = 0; mt < 2; ++mt)
#pragma unroll
        for (int ks = 0; ks < 2; ++ks)
            qa[mt][ks] = *(const bf16x8*)&Ps[(wave * 32 + mt * 16 + r) * LP + ks * 32 + q * 8];

    const bf16_t one_b = (bf16_t)1.0f;
    const bf16x8 ones = { one_b, one_b, one_b, one_b, one_b, one_b, one_b, one_b };

    f32x4 o[2][4] = {};
    f32x4 ol[2] = {};          // row-sums of P (l), same C-layout rows as o

    const int nk = CAUSAL ? (2 * qt + 2) : 16;
    stageKV(0, 0);

    for (int kt = 0; kt < nk; ++kt) {
        const int cur = kt & 1;
        __syncthreads();
        if (kt + 1 < nk) stageKV(cur ^ 1, kt + 1);

        // S = Q K^T (Q pre-scaled)
        f32x4 s[2][4] = {};
#pragma unroll
        for (int ks = 0; ks < 2; ++ks)
#pragma unroll
            for (int nt = 0; nt < 4; ++nt) {
                bf16x8 kb = *(const bf16x8*)&Ks[cur][ks][(nt * 16 + r) * 32 + (q * 8 ^ rsw)];
#pragma unroll
                for (int mt = 0; mt < 2; ++mt)
                    s[mt][nt] = __builtin_amdgcn_mfma_f32_16x16x32_bf16(qa[mt][ks], kb, s[mt][nt], 0, 0, 0);
            }

        if (CAUSAL) {
#pragma unroll
            for (int mt = 0; mt < 2; ++mt) {
                const int r0 = qt * 128 + wave * 32 + mt * 16;
                if (kt * 64 + 63 > r0) {
#pragma unroll
                    for (int nt = 0; nt < 4; ++nt) {
                        int kg = kt * 64 + nt * 16 + r;
#pragma unroll
                        for (int i2 = 0; i2 < 4; ++i2)
                            if (kg > r0 + q * 4 + i2) s[mt][nt][i2] = -INFINITY;
                    }
                }
            }
        }

        // P = exp(S); write to LDS (own rows only -> no barrier needed)
#pragma unroll
        for (int mt = 0; mt < 2; ++mt)
#pragma unroll
            for (int nt = 0; nt < 4; ++nt)
#pragma unroll
                for (int i2 = 0; i2 < 4; ++i2)
                    Ps[(wave * 32 + mt * 16 + q * 4 + i2) * LP + nt * 16 + r] =
                        (bf16_t)__expf(s[mt][nt][i2]);

        // O += P V ; l += P . 1
#pragma unroll
        for (int ks = 0; ks < 2; ++ks) {
            bf16x8 pa[2];
#pragma unroll
            for (int mt = 0; mt < 2; ++mt)
                pa[mt] = *(const bf16x8*)&Ps[(wave * 32 + mt * 16 + r) * LP + ks * 32 + q * 8];
#pragma unroll
            for (int dt = 0; dt < 4; ++dt) {
                bf16x8 vb = *(const bf16x8*)&Vs[cur][ks][(dt * 16 + r) * 32 + (q * 8 ^ rsw)];
#pragma unroll
                for (int mt = 0; mt < 2; ++mt)
                    o[mt][dt] = __builtin_amdgcn_mfma_f32_16x16x32_bf16(pa[mt], vb, o[mt][dt], 0, 0, 0);
            }
#pragma unroll
            for (int mt = 0; mt < 2; ++mt)
                ol[mt] = __builtin_amdgcn_mfma_f32_16x16x32_bf16(pa[mt], ones, ol[mt], 0, 0, 0);
        }
    }

    bf16_t* Ob = Op + (size_t)(b * T + qt * 128 + wave * 32) * 1024 + h * 64;
#pragma unroll
    for (int mt = 0; mt < 2; ++mt) {
        f32x4 inv;
#pragma unroll
        for (int i2 = 0; i2 < 4; ++i2) inv[i2] = 1.0f / ol[mt][i2];
#pragma unroll
        for (int dt = 0; dt < 4; ++dt)
#pragma unroll
            for (int i2 = 0; i2 < 4; ++i2)
                Ob[(size_t)(mt * 16 + q * 4 + i2) * 1024 + dt * 16 + r] = (bf16_t)(o[mt][dt][i2] * inv[i2]);
    }
}

// ---------------------------------------------------------------------------
extern "C" void kernel_launch(void* const* d_in, const int* in_sizes, int n_in,
                              void* d_out, int out_size, void* d_ws, size_t ws_size,
                              hipStream_t stream)
{
    const float* x     = (const float*)d_in[0];
    const float* enc   = (const float*)d_in[1];
    const float* sa_wq = (const float*)d_in[2];
    const float* sa_wk = (const float*)d_in[3];
    const float* sa_wv = (const float*)d_in[4];
    const float* sa_wo = (const float*)d_in[5];
    const float* sa_bo = (const float*)d_in[6];
    const float* ca_wq = (const float*)d_in[7];
    const float* ca_wk = (const float*)d_in[8];
    const float* ca_wv = (const float*)d_in[9];
    const float* ca_wo = (const float*)d_in[10];
    const float* ca_bo = (const float*)d_in[11];
    const float* ff_w1 = (const float*)d_in[12];
    const float* ff_b1 = (const float*)d_in[13];
    const float* ff_w2 = (const float*)d_in[14];
    const float* ff_b2 = (const float*)d_in[15];
    const float* ln1_g = (const float*)d_in[16];
    const float* ln1_b = (const float*)d_in[17];
    const float* ln2_g = (const float*)d_in[18];
    const float* ln2_b = (const float*)d_in[19];
    const float* ln3_g = (const float*)d_in[20];
    const float* ln3_b = (const float*)d_in[21];

    float* out = (float*)d_out;
    char* ws = (char*)d_ws;
    const size_t MB = 1024 * 1024;
    bf16_t* w_s3  = (bf16_t*)(ws +  0 * MB);   // self  [3072][1024] 6 MB (q|k|v)
    bf16_t* w_so  = (bf16_t*)(ws +  6 * MB);   // 2 MB
    bf16_t* w_c3  = (bf16_t*)(ws +  8 * MB);   // cross [3072][1024] 6 MB (q|k|v)
    bf16_t* w_co  = (bf16_t*)(ws + 14 * MB);   // 2 MB
    bf16_t* w_f1  = (bf16_t*)(ws + 16 * MB);   // [4096][1024] 8 MB
    bf16_t* w_f2  = (bf16_t*)(ws + 24 * MB);   // [1024][4096] 8 MB
    bf16_t* b_enc = (bf16_t*)(ws + 32 * MB);   // 8 MB
    bf16_t* b_ln  = (bf16_t*)(ws + 40 * MB);   // 8 MB
    bf16_t* b_q   = (bf16_t*)(ws + 48 * MB);   // [4096][1024] 8 MB
    bf16_t* b_k   = (bf16_t*)(ws + 56 * MB);   // [4096][1024] 8 MB
    bf16_t* b_vt  = (bf16_t*)(ws + 64 * MB);   // [4096(b,h,d)][1024] 8 MB
    bf16_t* b_at  = (bf16_t*)(ws + 72 * MB);   // [4096][1024] 8 MB
    float*  b_x1  = (float*) (ws + 80 * MB);   // fp32, 16 MB
    float*  b_x2  = (float*) (ws + 48 * MB);   // fp32, over b_q/b_k (dead)
    bf16_t* b_h1  = (bf16_t*)(ws + 64 * MB);   // [4096][4096] 32 MB (vt/at/x1 dead)

    const int M = 4096;  // B*T
    dim3 blk(256);

    // --- pre-pass: all weights -> bf16 [N,K] in ONE launch; enc -> bf16 ---
    WT16 wp;
    const float* srcs[8] = { sa_wq, sa_wk, sa_wv, sa_wo, ca_wq, ca_wk, ca_wv, ca_wo };
    bf16_t* dsts[8] = { w_s3, w_s3 + 1024*1024, w_s3 + 2048*1024, w_so,
                        w_c3, w_c3 + 1024*1024, w_c3 + 2048*1024, w_co };
    for (int z = 0; z < 8; ++z) {
        wp.src[z] = srcs[z]; wp.dst[z] = dsts[z];
        wp.srcN[z] = 1024; wp.dstK[z] = 1024; wp.k0b[z] = 0; wp.n0b[z] = 0;
    }
    for (int z = 8; z < 12; ++z) {   // ff_w1 [1024][4096] -> [4096][1024]
        wp.src[z] = ff_w1; wp.dst[z] = w_f1;
        wp.srcN[z] = 4096; wp.dstK[z] = 1024; wp.k0b[z] = 0; wp.n0b[z] = (z - 8) * 1024;
    }
    for (int z = 12; z < 16; ++z) {  // ff_w2 [4096][1024] -> [1024][4096]
        wp.src[z] = ff_w2; wp.dst[z] = w_f2;
        wp.srcN[z] = 1024; wp.dstK[z] = 4096; wp.k0b[z] = (z - 12) * 1024; wp.n0b[z] = 0;
    }
    wt16_kernel<<<dim3(16, 16, 16), blk, 0, stream>>>(wp);
    cvt_kernel<<<4096, blk, 0, stream>>>(enc, b_enc);

    // 1) ln1(x)
    ln_kernel<<<4096, blk, 0, stream>>>(x, ln1_g, ln1_b, b_ln);
    // 2) fused self QKV -> q (scaled), k row-major + v transposed
    gemm_qkv3<<<dim3(24, 32), blk, 0, stream>>>(b_ln, b_ln, w_s3, b_q, b_k, b_vt);
    // 3) causal self-attention (pair-balanced schedule: qt & 7-qt same CU)
    attn_mfma_kernel<1><<<dim3(8, 16, 4), blk, 0, stream>>>(b_q, b_k, b_vt, b_at);
    // 4) out-proj + bias + residual(x) -> x1 (fp32)
    gemm_bf16<64,2,0,1,0,1><<<dim3(16, 32), blk, 0, stream>>>(
        b_at, w_so, sa_bo, x, b_x1, M, 1024, 1024);
    // 5) ln2(x1)
    ln_kernel<<<4096, blk, 0, stream>>>(b_x1, ln2_g, ln2_b, b_ln);
    // 6) fused cross projections: q from ln2(x1), k/v from encoder_out
    gemm_qkv3<<<dim3(24, 32), blk, 0, stream>>>(b_ln, b_enc, w_c3, b_q, b_k, b_vt);
    // 7) full cross-attention (XCD-swizzled, balanced by nature)
    attn_mfma_kernel<0><<<dim3(8, 16, 4), blk, 0, stream>>>(b_q, b_k, b_vt, b_at);
    // 8) out-proj + bias + residual(x1) -> x2 (fp32)
    gemm_bf16<64,2,0,1,0,1><<<dim3(16, 32), blk, 0, stream>>>(
        b_at, w_co, ca_bo, b_x1, b_x2, M, 1024, 1024);
    // 9) ln3(x2)
    ln_kernel<<<4096, blk, 0, stream>>>(b_x2, ln3_g, ln3_b, b_ln);
    // 10) FFN up: relu(ln3 @ w1 + b1) -> h1 (bf16) — 256^2 8-phase kernel
    //     (grid 256 blocks = 1/CU; 8 waves; T2+T3+T4+T5 combo)
    gemm_256<<<dim3(16, 16), dim3(512), 0, stream>>>(
        b_ln, w_f1, ff_b1, b_h1, M, 4096, 1024);
    // 11) FFN down + bias + residual(x2) -> out (R0 config — best measured)
    gemm_bf16<64,2,0,1,0,1><<<dim3(16, 32), blk, 0, stream>>>(
        b_h1, w_f2, ff_b2, b_x2, out, M, 1024, 4096);
}